// Round 1
// 182.258 us; speedup vs baseline: 1.0254x; 1.0254x over previous
//
#include <hip/hip_runtime.h>

#define BB   4
#define CC   256
#define HH   128
#define WW   128
#define PAD  4
#define KOUT 81

#define TH   8        // output rows per block (one per wave)
#define SW   16       // output cols per block (one MFMA M-tile)
#define KC   32       // channels per chunk (one MFMA K)
#define NCHUNK (CC / KC)
#define AK   40       // padded K-stride per LDS point (80 B: 16B-aligned, stride-20-words reads conflict-free)

typedef _Float16 half8 __attribute__((ext_vector_type(8)));
typedef float    f32x4 __attribute__((ext_vector_type(4)));

__global__ __launch_bounds__(512, 4)
void corr_mfma3(const float* __restrict__ i1,
                const float* __restrict__ i2,
                float* __restrict__ out)
{
    // LDS layout unchanged from previous version: [pt][ch], AK-strided.
    // A: 128 pts (8 rows x 16 m), B: 512 slots (16 rows x 32 q; q<24 valid).
    __shared__ _Float16 Ald[128 * AK];   // 10240 B
    __shared__ _Float16 Bld[512 * AK];   // 40960 B

    const int t    = threadIdx.x;
    const int wave = t >> 6;
    const int lane = t & 63;
    const int l15  = lane & 15;
    const int quad = lane >> 4;

    const int b  = blockIdx.z;
    const int h0 = blockIdx.y * TH;
    const int w0 = blockIdx.x * SW;

    const size_t strideC = (size_t)HH * WW;
    const float* i1b = i1 + (size_t)b * CC * strideC;
    const float* i2b = i2 + (size_t)b * CC * strideC;

    // ---- staging role: each thread owns a (4-col x 8-channel) granule.
    // Loads: 8 x dwordx4 along W (16B-aligned; halo==4 => group all-valid or all-invalid).
    // Writes: register-transpose -> 4 x ds_write_b128 into the [pt][ch] layout.
    // B: threads 0..383 = 16 rows x 6 col-groups x 4 ch8-groups
    // A: threads 384..511 = 8 rows x 4 col-groups x 4 ch8-groups
    bool valid;
    const float* gp;
    _Float16* ld0;

    if (t < 384) {
        const int g   = t % 6;           // col-group: cols w0-4+4g .. +3
        const int t6  = t / 6;           // 0..63
        const int ch8 = t6 & 3;          // channel sub-block (x8)
        const int sr  = t6 >> 2;         // B tile row 0..15
        const int row  = h0 - PAD + sr;
        const int col0 = w0 - PAD + 4 * g;
        valid = (row >= 0) && (row < HH) && (col0 >= 0) && (col0 + 3 < WW);
        gp  = i2b + (size_t)(valid ? row : 0) * WW + (valid ? col0 : 0)
                  + (size_t)ch8 * 8 * strideC;
        ld0 = &Bld[(sr * 32 + 4 * g) * AK + ch8 * 8];
    } else {
        const int i   = t - 384;
        const int g   = i & 3;           // col-group: cols w0+4g .. +3
        const int t4  = i >> 2;          // 0..31
        const int ch8 = t4 & 3;
        const int sr  = t4 >> 2;         // A tile row 0..7
        valid = true;
        gp  = i1b + (size_t)(h0 + sr) * WW + (w0 + 4 * g)
                  + (size_t)ch8 * 8 * strideC;
        ld0 = &Ald[(sr * 16 + 4 * g) * AK + ch8 * 8];
    }

    f32x4 acc[9][2];
#pragma unroll
    for (int dy = 0; dy < 9; ++dy) {
        acc[dy][0] = (f32x4){0.f, 0.f, 0.f, 0.f};
        acc[dy][1] = (f32x4){0.f, 0.f, 0.f, 0.f};
    }

    f32x4 L[8];

    // ---- prologue: stage chunk 0; invalid threads zero their slots ONCE
    // (their pts stay zero for the whole kernel -- no loads/writes in the loop).
    if (valid) {
#pragma unroll
        for (int j = 0; j < 8; ++j)
            L[j] = *(const f32x4*)(gp + (size_t)j * strideC);
#pragma unroll
        for (int i = 0; i < 4; ++i) {
            half8 hv;
#pragma unroll
            for (int k = 0; k < 8; ++k) hv[k] = (_Float16)L[k][i];
            *(half8*)(ld0 + i * AK) = hv;
        }
    } else {
        const half8 z = (half8){0, 0, 0, 0, 0, 0, 0, 0};
#pragma unroll
        for (int i = 0; i < 4; ++i)
            *(half8*)(ld0 + i * AK) = z;
    }
    __syncthreads();

#pragma unroll 1
    for (int ch = 0; ch < NCHUNK; ++ch) {
        // ---- prefetch next chunk's globals into registers (pure loads, no
        // selects: first vmcnt wait happens at the convert phase AFTER sync1,
        // so ~3.6k cycles of LDS/MFMA cover the HBM latency) ----
        if (valid && (ch + 1 < NCHUNK)) {
            const float* gnext = gp + (size_t)(ch + 1) * KC * strideC;
#pragma unroll
            for (int j = 0; j < 8; ++j)
                L[j] = *(const f32x4*)(gnext + (size_t)j * strideC);
        }

        // ---- compute current chunk: one output row per wave, 9 dy x 2 N-tiles ----
        {
            const half8 a = *(const half8*)&Ald[(wave * 16 + l15) * AK + quad * 8];
#pragma unroll
            for (int dy = 0; dy < 9; ++dy) {
                const int r = wave + dy;
                const half8 b0 = *(const half8*)&Bld[(r * 32 + l15) * AK + quad * 8];
                acc[dy][0] = __builtin_amdgcn_mfma_f32_16x16x32_f16(a, b0, acc[dy][0], 0, 0, 0);
                const half8 b1 = *(const half8*)&Bld[(r * 32 + 16 + l15) * AK + quad * 8];
                acc[dy][1] = __builtin_amdgcn_mfma_f32_16x16x32_f16(a, b1, acc[dy][1], 0, 0, 0);
            }
        }

        if (ch + 1 < NCHUNK) {
            __syncthreads();   // all waves done reading LDS for chunk ch
            if (valid) {
#pragma unroll
                for (int i = 0; i < 4; ++i) {
                    half8 hv;
#pragma unroll
                    for (int k = 0; k < 8; ++k) hv[k] = (_Float16)L[k][i];
                    *(half8*)(ld0 + i * AK) = hv;
                }
            }
            __syncthreads();   // chunk ch+1 visible
        }
    }

    // ---- epilogue: D[p][q], p = quad*4+reg, q = l15 + 16*tt, dx = q - p ----
    const int h = h0 + wave;
#pragma unroll
    for (int dy = 0; dy < 9; ++dy) {
#pragma unroll
        for (int tt = 0; tt < 2; ++tt) {
#pragma unroll
            for (int reg = 0; reg < 4; ++reg) {
                const int p  = quad * 4 + reg;
                const int dx = l15 + 16 * tt - p;
                if (dx >= 0 && dx <= 8) {
                    out[(((size_t)b * KOUT + (dy * 9 + dx)) * HH + h) * WW + (w0 + p)] =
                        acc[dy][tt][reg];
                }
            }
        }
    }
}

extern "C" void kernel_launch(void* const* d_in, const int* in_sizes, int n_in,
                              void* d_out, int out_size, void* d_ws, size_t ws_size,
                              hipStream_t stream)
{
    (void)in_sizes; (void)n_in; (void)d_ws; (void)ws_size; (void)out_size;
    const float* i1 = (const float*)d_in[0];
    const float* i2 = (const float*)d_in[1];
    float* out = (float*)d_out;

    dim3 grid(WW / SW, HH / TH, BB);   // (8, 16, 4) = 512 blocks, 2 per CU
    dim3 block(512);
    corr_mfma3<<<grid, block, 0, stream>>>(i1, i2, out);
}

// Round 2
// 178.069 us; speedup vs baseline: 1.0496x; 1.0235x over previous
//
#include <hip/hip_runtime.h>

#define BB   4
#define CC   256
#define HH   128
#define WW   128
#define PAD  4
#define KOUT 81

#define TH   8        // output rows per block (one per wave)
#define SW   16       // output cols per block (one MFMA M-tile)
#define KC   32       // channels per chunk (one MFMA K)
#define NCHUNK (CC / KC)
#define AK   40       // padded K-stride per LDS point (80 B: 16B-aligned, stride-20-words reads conflict-free)

typedef _Float16 half8 __attribute__((ext_vector_type(8)));
typedef float    f32x4 __attribute__((ext_vector_type(4)));

__global__ __launch_bounds__(512, 4)
void corr_mfma4(const float* __restrict__ i1,
                const float* __restrict__ i2,
                float* __restrict__ out)
{
    // LDS layout: [pt][ch], AK-strided.
    // A: 128 pts (8 rows x 16 m), B: 512 slots (16 rows x 32 q; q<24 valid).
    __shared__ _Float16 Ald[128 * AK];   // 10240 B
    __shared__ _Float16 Bld[512 * AK];   // 40960 B

    const int t    = threadIdx.x;
    const int wave = t >> 6;
    const int lane = t & 63;
    const int l15  = lane & 15;
    const int quad = lane >> 4;

    // ---- XCD-chunked block swizzle ----
    // HW round-robins linear block ID % 8 -> XCD. Raw mapping puts all 8
    // x-strips of one (y,z) tile-row on 8 DIFFERENT XCDs: each XCD streams
    // 64-B sectors at stride 512 B (12.5% density) -> DRAM-hostile, and the
    // B column-halo duplicates across XCDs. Chunked remap gives each XCD a
    // contiguous row band (all x, 8 consecutive y, one batch): sequential
    // full-row streams, ~2.2 MB/chunk working set fits the 4 MB XCD L2.
    const int raw     = blockIdx.x + 8 * blockIdx.y + 128 * blockIdx.z;
    const int logical = (raw & 7) * 64 + (raw >> 3);   // bijective: 512 = 8*64
    const int b  = logical >> 7;
    const int h0 = ((logical >> 3) & 15) * TH;
    const int w0 = (logical & 7) * SW;

    const size_t strideC = (size_t)HH * WW;
    const float* i1b = i1 + (size_t)b * CC * strideC;
    const float* i2b = i2 + (size_t)b * CC * strideC;

    // ---- staging role: each thread owns a (4-col x 8-channel) granule.
    // Loads: 8 x dwordx4 along W (16B-aligned; halo==4 => group all-valid or all-invalid).
    // Writes: register-transpose -> 4 x ds_write_b128 into the [pt][ch] layout.
    // B: threads 0..383 = 16 rows x 6 col-groups x 4 ch8-groups
    // A: threads 384..511 = 8 rows x 4 col-groups x 4 ch8-groups
    bool valid;
    const float* gp;
    _Float16* ld0;

    if (t < 384) {
        const int g   = t % 6;           // col-group: cols w0-4+4g .. +3
        const int t6  = t / 6;           // 0..63
        const int ch8 = t6 & 3;          // channel sub-block (x8)
        const int sr  = t6 >> 2;         // B tile row 0..15
        const int row  = h0 - PAD + sr;
        const int col0 = w0 - PAD + 4 * g;
        valid = (row >= 0) && (row < HH) && (col0 >= 0) && (col0 + 3 < WW);
        gp  = i2b + (size_t)(valid ? row : 0) * WW + (valid ? col0 : 0)
                  + (size_t)ch8 * 8 * strideC;
        ld0 = &Bld[(sr * 32 + 4 * g) * AK + ch8 * 8];
    } else {
        const int i   = t - 384;
        const int g   = i & 3;           // col-group: cols w0+4g .. +3
        const int t4  = i >> 2;          // 0..31
        const int ch8 = t4 & 3;
        const int sr  = t4 >> 2;         // A tile row 0..7
        valid = true;
        gp  = i1b + (size_t)(h0 + sr) * WW + (w0 + 4 * g)
                  + (size_t)ch8 * 8 * strideC;
        ld0 = &Ald[(sr * 16 + 4 * g) * AK + ch8 * 8];
    }

    f32x4 acc[9][2];
#pragma unroll
    for (int dy = 0; dy < 9; ++dy) {
        acc[dy][0] = (f32x4){0.f, 0.f, 0.f, 0.f};
        acc[dy][1] = (f32x4){0.f, 0.f, 0.f, 0.f};
    }

    f32x4 L[8];

    // ---- prologue: stage chunk 0; invalid threads zero their slots ONCE
    // (their pts stay zero for the whole kernel -- no loads/writes in the loop).
    if (valid) {
#pragma unroll
        for (int j = 0; j < 8; ++j)
            L[j] = *(const f32x4*)(gp + (size_t)j * strideC);
#pragma unroll
        for (int i = 0; i < 4; ++i) {
            half8 hv;
#pragma unroll
            for (int k = 0; k < 8; ++k) hv[k] = (_Float16)L[k][i];
            *(half8*)(ld0 + i * AK) = hv;
        }
    } else {
        const half8 z = (half8){0, 0, 0, 0, 0, 0, 0, 0};
#pragma unroll
        for (int i = 0; i < 4; ++i)
            *(half8*)(ld0 + i * AK) = z;
    }
    __syncthreads();

#pragma unroll 1
    for (int ch = 0; ch < NCHUNK; ++ch) {
        // ---- prefetch next chunk's globals into registers (pure loads, no
        // selects: first vmcnt wait happens at the convert phase AFTER sync1,
        // so the LDS/MFMA compute phase covers the HBM latency) ----
        if (valid && (ch + 1 < NCHUNK)) {
            const float* gnext = gp + (size_t)(ch + 1) * KC * strideC;
#pragma unroll
            for (int j = 0; j < 8; ++j)
                L[j] = *(const f32x4*)(gnext + (size_t)j * strideC);
        }

        // ---- compute current chunk: one output row per wave, 9 dy x 2 N-tiles ----
        {
            const half8 a = *(const half8*)&Ald[(wave * 16 + l15) * AK + quad * 8];
#pragma unroll
            for (int dy = 0; dy < 9; ++dy) {
                const int r = wave + dy;
                const half8 b0 = *(const half8*)&Bld[(r * 32 + l15) * AK + quad * 8];
                acc[dy][0] = __builtin_amdgcn_mfma_f32_16x16x32_f16(a, b0, acc[dy][0], 0, 0, 0);
                const half8 b1 = *(const half8*)&Bld[(r * 32 + 16 + l15) * AK + quad * 8];
                acc[dy][1] = __builtin_amdgcn_mfma_f32_16x16x32_f16(a, b1, acc[dy][1], 0, 0, 0);
            }
        }

        if (ch + 1 < NCHUNK) {
            __syncthreads();   // all waves done reading LDS for chunk ch
            if (valid) {
#pragma unroll
                for (int i = 0; i < 4; ++i) {
                    half8 hv;
#pragma unroll
                    for (int k = 0; k < 8; ++k) hv[k] = (_Float16)L[k][i];
                    *(half8*)(ld0 + i * AK) = hv;
                }
            }
            __syncthreads();   // chunk ch+1 visible
        }
    }

    // ---- epilogue: D[p][q], p = quad*4+reg, q = l15 + 16*tt, dx = q - p ----
    const int h = h0 + wave;
#pragma unroll
    for (int dy = 0; dy < 9; ++dy) {
#pragma unroll
        for (int tt = 0; tt < 2; ++tt) {
#pragma unroll
            for (int reg = 0; reg < 4; ++reg) {
                const int p  = quad * 4 + reg;
                const int dx = l15 + 16 * tt - p;
                if (dx >= 0 && dx <= 8) {
                    out[(((size_t)b * KOUT + (dy * 9 + dx)) * HH + h) * WW + (w0 + p)] =
                        acc[dy][tt][reg];
                }
            }
        }
    }
}

extern "C" void kernel_launch(void* const* d_in, const int* in_sizes, int n_in,
                              void* d_out, int out_size, void* d_ws, size_t ws_size,
                              hipStream_t stream)
{
    (void)in_sizes; (void)n_in; (void)d_ws; (void)ws_size; (void)out_size;
    const float* i1 = (const float*)d_in[0];
    const float* i2 = (const float*)d_in[1];
    float* out = (float*)d_out;

    dim3 grid(WW / SW, HH / TH, BB);   // (8, 16, 4) = 512 blocks, 2 per CU
    dim3 block(512);
    corr_mfma4<<<grid, block, 0, stream>>>(i1, i2, out);
}